// Round 5
// baseline (2102.406 us; speedup 1.0000x reference)
//
#include <hip/hip_runtime.h>

#define LAMF 0.1f
#define LRF  0.01f
#define B1F  0.9f
#define B2F  0.99f
#define EPSF 1e-8f

constexpr int NB = 32;
constexpr int PLANE = 61 * 61;             // 3721
constexpr int USZ = NB * 64 * PLANE;       // u/m/v element count
constexpr int ESZ = NB * 256 * 256;
constexpr int FSZ = 16 * 16 * 64;
// act_pad: [b][c][62 rows][68 slots]; row 61 = permanent zero row,
// slots 0..3 and 65..67 = zero j-pad; interior j at slot j+4.
constexpr int APROW = 68;
constexpr int APPL  = 62 * APROW;          // 4216
constexpr int APSZ  = NB * 64 * APPL;

// ---------------------------------------------------------------------------
// f1[r][c][li][s][k] = filt[4*(3-li)+s][4*(3-k)+r][c]
// ---------------------------------------------------------------------------
__global__ __launch_bounds__(256) void permute_filt(const float* __restrict__ filt,
                                                    float* __restrict__ f1) {
    int o = blockIdx.x * 256 + threadIdx.x;
    if (o >= FSZ) return;
    int k  = o & 3;
    int s  = (o >> 2) & 3;
    int ii = (o >> 4) & 3;
    int c  = (o >> 6) & 63;
    int r  = o >> 12;
    int kh = 4 * (3 - ii) + s;
    int kw = 4 * (3 - k) + r;
    f1[o] = filt[(kh * 16 + kw) * 64 + c];
}

// ---------------------------------------------------------------------------
// ek: e = img - conv_transpose(act).  512 threads = 8 waves = (rh x cq).
// Wave role: rh picks r-pair {2rh, 2rh+1}; cq picks 16-channel quarter.
// lane = (w band 0..3, xh x-chunk 0..15); thread outputs rr(2) x s(4) x d(4)
// at y = 4*(p0+w)+s, x = 16*xh + 4*d + 2*rh + rr, all from ONE 8-dword act
// window per (cc,li).  Cross-wave c-reduce via LDS (cq!=0 write, cq==0 sum).
// ---------------------------------------------------------------------------
#define EK_FMA2(A0, A1, fp)                                                   \
  {                                                                           \
    float av[8] = {A0.x, A0.y, A0.z, A0.w, A1.x, A1.y, A1.z, A1.w};           \
    _Pragma("unroll")                                                         \
    for (int rr = 0; rr < 2; ++rr) {                                          \
      const float* fs = (fp) + rr * 4096;                                     \
      _Pragma("unroll")                                                       \
      for (int s = 0; s < 4; ++s) {                                           \
        _Pragma("unroll")                                                     \
        for (int d = 0; d < 4; ++d) {                                         \
          acc[rr][s][d] += av[1 + d + 0] * fs[s * 4 + 0]                      \
                         + av[1 + d + 1] * fs[s * 4 + 1]                      \
                         + av[1 + d + 2] * fs[s * 4 + 2]                      \
                         + av[1 + d + 3] * fs[s * 4 + 3];                     \
        }                                                                     \
      }                                                                       \
    }                                                                         \
  }

__global__ __launch_bounds__(512, 4) void ek(const float* __restrict__ act,
                                             const float* __restrict__ img,
                                             const float* __restrict__ f1,
                                             float* __restrict__ e) {
    __shared__ __align__(16) float red[3 * 2 * 64 * 32];   // 48 KB
    int bid  = blockIdx.x;                    // 512 = 8 XCD * 64
    int n    = (bid & 7) * 64 + (bid >> 3);
    int b    = n >> 4;
    int p0   = (n & 15) * 4;
    int tid  = threadIdx.x;
    int wave = __builtin_amdgcn_readfirstlane(tid >> 6);
    int rh   = wave >> 2;                     // r in {2rh, 2rh+1}
    int cq   = wave & 3;                      // c in [16cq, 16cq+16)
    int lane = tid & 63;
    int w    = lane >> 4;
    int xh   = lane & 15;

    const float* rp0;
    const float* rp1;
    const float* rp2;
    const float* rp3;
    {
        int i0 = p0 + w - 3;
#define EK_ROW(li)  ((i0 + (li) >= 0 && i0 + (li) <= 60) ? i0 + (li) : 61)
        rp0 = act + ((size_t)((b * 64 + cq * 16) * 62 + EK_ROW(0))) * APROW + 4 * xh;
        rp1 = act + ((size_t)((b * 64 + cq * 16) * 62 + EK_ROW(1))) * APROW + 4 * xh;
        rp2 = act + ((size_t)((b * 64 + cq * 16) * 62 + EK_ROW(2))) * APROW + 4 * xh;
        rp3 = act + ((size_t)((b * 64 + cq * 16) * 62 + EK_ROW(3))) * APROW + 4 * xh;
#undef EK_ROW
    }
    const float* fb = f1 + rh * 8192 + cq * 1024;   // + cc*64 + li*16 (+rr*4096)

    float acc[2][4][4] = {};
    float4 Xa = *(const float4*)rp0;
    float4 Xb = *(const float4*)(rp0 + 4);
    float4 Ya, Yb;
    for (int cc = 0; cc < 16; ++cc) {
        const float* fp = fb + cc * 64;
        Ya = *(const float4*)rp1; Yb = *(const float4*)(rp1 + 4);
        EK_FMA2(Xa, Xb, fp);                        // li = 0
        Xa = *(const float4*)rp2; Xb = *(const float4*)(rp2 + 4);
        EK_FMA2(Ya, Yb, fp + 16);                   // li = 1
        Ya = *(const float4*)rp3; Yb = *(const float4*)(rp3 + 4);
        EK_FMA2(Xa, Xb, fp + 32);                   // li = 2
        rp0 += APPL; rp1 += APPL; rp2 += APPL; rp3 += APPL;
        Xa = *(const float4*)rp0; Xb = *(const float4*)(rp0 + 4);  // (cc+1, li0)
        EK_FMA2(Ya, Yb, fp + 48);                   // li = 3
    }

    // cross-wave c reduction
    if (cq != 0) {
        float* rb = red + (((cq - 1) * 2 + rh) * 64 + lane) * 32;
#pragma unroll
        for (int rr = 0; rr < 2; ++rr)
#pragma unroll
            for (int s = 0; s < 4; ++s)
                *(float4*)(rb + (rr * 4 + s) * 4) =
                    make_float4(acc[rr][s][0], acc[rr][s][1],
                                acc[rr][s][2], acc[rr][s][3]);
    }
    __syncthreads();
    if (cq == 0) {
#pragma unroll
        for (int q = 0; q < 3; ++q) {
            const float* rb = red + ((q * 2 + rh) * 64 + lane) * 32;
#pragma unroll
            for (int rr = 0; rr < 2; ++rr)
#pragma unroll
                for (int s = 0; s < 4; ++s) {
                    float4 t = *(const float4*)(rb + (rr * 4 + s) * 4);
                    acc[rr][s][0] += t.x;
                    acc[rr][s][1] += t.y;
                    acc[rr][s][2] += t.z;
                    acc[rr][s][3] += t.w;
                }
        }
#pragma unroll
        for (int s = 0; s < 4; ++s) {
            size_t gi = ((size_t)b * 256 + 4 * (p0 + w) + s) * 256
                      + 16 * xh + 2 * rh;
#pragma unroll
            for (int d = 0; d < 4; ++d) {
                float2 iv = *(const float2*)(img + gi + 4 * d);
                float2 ev;
                ev.x = iv.x - acc[0][s][d];
                ev.y = iv.y - acc[1][s][d];
                *(float2*)(e + gi + 4 * d) = ev;
            }
        }
    }
}

// ---------------------------------------------------------------------------
// gk: conv(e,filt) + fused Adam.  1 output row per block (no bounds checks on
// the 16-row e patch), 1952 blocks -> ~30 waves/CU.
// MODE 0: first iter (u=m=v=0 on input).  MODE 1: middle.  MODE 2: last iter,
// writes ONLY the NHWC output relu(u_new - lam).
// ---------------------------------------------------------------------------
template <int MODE>
__global__ __launch_bounds__(256, 6) void gk(float* __restrict__ u,
                                             float* __restrict__ mbuf,
                                             float* __restrict__ vbuf,
                                             float* __restrict__ actp,
                                             float* __restrict__ out,
                                             const float* __restrict__ e,
                                             const float* __restrict__ filt,
                                             float bc1, float bc2) {
    __shared__ __align__(16) float lds[16 * 256];
    int bid = blockIdx.x;                      // 1952 = 8 * 244
    int n   = (bid & 7) * 244 + (bid >> 3);
    int b   = n / 61;
    int i   = n % 61;
    int tid = threadIdx.x;
    int j   = tid & 63;
    int c0  = __builtin_amdgcn_readfirstlane((tid >> 6) * 16);
    int jc  = (j < 61) ? j : 60;

    const float4* e4 = (const float4*)(e + ((size_t)b * 256 + 4 * i) * 256);
    float4* l4 = (float4*)lds;
#pragma unroll
    for (int q = 0; q < 4; ++q) l4[tid + q * 256] = e4[tid + q * 256];
    __syncthreads();

    float acc[16] = {};
    for (int kh = 0; kh < 16; ++kh) {
#pragma unroll
        for (int gw = 0; gw < 4; ++gw) {
            float4 ea = l4[kh * 64 + jc + gw];
            float ev[4] = {ea.x, ea.y, ea.z, ea.w};
#pragma unroll
            for (int t = 0; t < 4; ++t) {
                const float* fc = filt + ((kh * 16 + 4 * gw + t) * 64 + c0);
#pragma unroll
                for (int mm = 0; mm < 16; ++mm)
                    acc[mm] += ev[t] * fc[mm];
            }
        }
    }

    if (j < 61) {
        if (MODE == 2) {
            float ov[16];
#pragma unroll
            for (int mm = 0; mm < 16; ++mm) {
                size_t idx = (size_t)(b * 64 + c0 + mm) * PLANE + i * 61 + j;
                float uu = u[idx];
                float a  = fmaxf(uu - LAMF, 0.f);
                float gg = acc[mm] + a - uu;
                float mv = B1F * mbuf[idx] + (1.f - B1F) * gg;
                float vv = B2F * vbuf[idx] + (1.f - B2F) * gg * gg;
                float un = uu + LRF * (mv / bc1) / (sqrtf(vv / bc2) + EPSF);
                ov[mm] = fmaxf(un - LAMF, 0.f);
            }
            float* op = out + (((size_t)b * 61 + i) * 61 + j) * 64 + c0;
#pragma unroll
            for (int q = 0; q < 4; ++q)
                *(float4*)(op + 4 * q) = make_float4(ov[4 * q], ov[4 * q + 1],
                                                     ov[4 * q + 2], ov[4 * q + 3]);
        } else {
#pragma unroll
            for (int mm = 0; mm < 16; ++mm) {
                size_t idx = (size_t)(b * 64 + c0 + mm) * PLANE + i * 61 + j;
                float uu, a, mprev, vprev;
                if (MODE == 0) {
                    uu = 0.f; a = 0.f; mprev = 0.f; vprev = 0.f;
                } else {
                    uu = u[idx];
                    a  = fmaxf(uu - LAMF, 0.f);
                    mprev = mbuf[idx];
                    vprev = vbuf[idx];
                }
                float gg = acc[mm] + a - uu;
                float mv = B1F * mprev + (1.f - B1F) * gg;
                float vv = B2F * vprev + (1.f - B2F) * gg * gg;
                mbuf[idx] = mv;
                vbuf[idx] = vv;
                float un = uu + LRF * (mv / bc1) / (sqrtf(vv / bc2) + EPSF);
                u[idx] = un;
                actp[(size_t)(b * 64 + c0 + mm) * APPL + (size_t)i * APROW + 4 + j]
                    = fmaxf(un - LAMF, 0.f);
            }
        }
    }
}

// ---------------------------------------------------------------------------
extern "C" void kernel_launch(void* const* d_in, const int* in_sizes, int n_in,
                              void* d_out, int out_size, void* d_ws, size_t ws_size,
                              hipStream_t stream) {
    const float* img  = (const float*)d_in[0];
    const float* filt = (const float*)d_in[1];
    float* out = (float*)d_out;

    float* u    = (float*)d_ws;
    float* mbuf = u + USZ;
    float* vbuf = mbuf + USZ;
    float* e    = vbuf + USZ;
    float* actp = e + ESZ;
    float* f1   = actp + APSZ;   // f1 AFTER actp: ek's tail prefetch overruns
                                 // actp by 32B into f1 (valid memory, unused)

    hipMemsetAsync(actp, 0, (size_t)APSZ * sizeof(float), stream);
    permute_filt<<<FSZ / 256, 256, 0, stream>>>(filt, f1);
    // t = 0: u = 0 -> act = 0 -> e = img exactly
    hipMemcpyAsync(e, img, (size_t)ESZ * sizeof(float), hipMemcpyDeviceToDevice,
                   stream);

    float b1p = B1F, b2p = B2F;
    gk<0><<<1952, 256, 0, stream>>>(u, mbuf, vbuf, actp, out, e, filt,
                                    1.f - b1p, 1.f - b2p);
    for (int t = 1; t < 9; ++t) {
        b1p *= B1F;
        b2p *= B2F;
        ek<<<512, 512, 0, stream>>>(actp, img, f1, e);
        gk<1><<<1952, 256, 0, stream>>>(u, mbuf, vbuf, actp, out, e, filt,
                                        1.f - b1p, 1.f - b2p);
    }
    b1p *= B1F;
    b2p *= B2F;
    ek<<<512, 512, 0, stream>>>(actp, img, f1, e);
    gk<2><<<1952, 256, 0, stream>>>(u, mbuf, vbuf, actp, out, e, filt,
                                    1.f - b1p, 1.f - b2p);
}